// Round 4
// baseline (805.118 us; speedup 1.0000x reference)
//
#include <hip/hip_runtime.h>

// Correctly-rounded float decay constants
#define DEC1 0.36787944117144233f   // exp(-1)    : psp1 decay, layer1 refractory
#define DEC2 0.60653065971263342f   // exp(-1/2)  : psp2 decay, layer2 refractory
#define DEC3 0.77880078307140487f   // exp(-1/4)  : psp3 decay, layer3 refractory

// ---------------------------------------------------------------------------
// Weight re-layout into d_ws:  w1r[tap][o] (400 f)  w2r[tap][o] (576 f)
// wupr[o][di][dj][c] pre-flipped for conv_transpose (64 f). Total 1040 floats.
// ---------------------------------------------------------------------------
__global__ void prep_weights(const float* __restrict__ w1,
                             const float* __restrict__ w2,
                             const float* __restrict__ wup,
                             float* __restrict__ wr)
{
    int i = blockIdx.x * 256 + threadIdx.x;
    if (i < 400) {
        int o = i & 7, tap = i >> 3;
        int c = tap / 25, rem = tap % 25, ky = rem / 5, kx = rem % 5;
        wr[i] = w1[((o * 2 + c) * 5 + ky) * 5 + kx];
    }
    if (i < 576) {
        int o = i & 7, tap = i >> 3;
        int c = tap / 9, rem = tap % 9, ky = rem / 3, kx = rem % 3;
        wr[400 + i] = w2[((o * 8 + c) * 3 + ky) * 3 + kx];
    }
    if (i < 64) {
        int c = i & 7, r = i >> 3;
        int dj = r & 1, di = (r >> 1) & 1, o = r >> 2;
        wr[976 + i] = wup[((o * 8 + c) * 2 + (1 - di)) * 2 + (1 - dj)];
    }
}

// spike + following psp, 4 consecutive timesteps (u = float4 over t)
static __device__ __forceinline__ float4 spike_psp4(float4 u, float th, float dref,
                                                    float dq, float& r, float& q)
{
    float4 qv; float v, s;
    v = __fadd_rn(u.x, r); s = (v >= th) ? 1.f : 0.f;
    r = __fsub_rn(__fmul_rn(dref, r), __fmul_rn(th, s));
    q = __fadd_rn(__fmul_rn(dq, q), s); qv.x = q;
    v = __fadd_rn(u.y, r); s = (v >= th) ? 1.f : 0.f;
    r = __fsub_rn(__fmul_rn(dref, r), __fmul_rn(th, s));
    q = __fadd_rn(__fmul_rn(dq, q), s); qv.y = q;
    v = __fadd_rn(u.z, r); s = (v >= th) ? 1.f : 0.f;
    r = __fsub_rn(__fmul_rn(dref, r), __fmul_rn(th, s));
    q = __fadd_rn(__fmul_rn(dq, q), s); qv.z = q;
    v = __fadd_rn(u.w, r); s = (v >= th) ? 1.f : 0.f;
    r = __fsub_rn(__fmul_rn(dref, r), __fmul_rn(th, s));
    q = __fadd_rn(__fmul_rn(dq, q), s); qv.w = q;
    return qv;
}

// final spike (emits hard spikes), 4 timesteps
static __device__ __forceinline__ float4 spike4(float4 u, float th, float dref, float& r)
{
    float4 ov; float v, s;
    v = __fadd_rn(u.x, r); s = (v >= th) ? 1.f : 0.f;
    r = __fsub_rn(__fmul_rn(dref, r), __fmul_rn(th, s)); ov.x = s;
    v = __fadd_rn(u.y, r); s = (v >= th) ? 1.f : 0.f;
    r = __fsub_rn(__fmul_rn(dref, r), __fmul_rn(th, s)); ov.y = s;
    v = __fadd_rn(u.z, r); s = (v >= th) ? 1.f : 0.f;
    r = __fsub_rn(__fmul_rn(dref, r), __fmul_rn(th, s)); ov.z = s;
    v = __fadd_rn(u.w, r); s = (v >= th) ? 1.f : 0.f;
    r = __fsub_rn(__fmul_rn(dref, r), __fmul_rn(th, s)); ov.w = s;
    return ov;
}

// NOTE: macro params must not be named w/x/y/z — they'd capture the .w member
// access in the expansion (R2's compile failure).
#define FMA4(ACC_, W_, D_) { ACC_.x += (W_)*(D_).x; ACC_.y += (W_)*(D_).y; \
                             ACC_.z += (W_)*(D_).z; ACC_.w += (W_)*(D_).w; }

// ---------------------------------------------------------------------------
// Fused SNN megakernel, R3 (= R2 design): 4x8 core tile (1024 blocks ->
// 4 blocks/CU, 16 waves/CU), T-chunk = 8 (two float4s, 32 B contiguous
// stores), all four stages use (nearly) all 256 lanes:
//   A: psp1 on 10x14 region, 140 threads x 2 ch
//   B: conv5x5+spike1+psp2 on 6x10 region; wave w handles och {2w,2w+1}
//      (wave-uniform -> scalar weight loads), lanes 0..59, 2 units/thread
//   C: conv3x3+spike2+psp3 on 4x8 core; 256 threads x 1 (och,px) unit,
//      weights from LDS (2 distinct addrs/wave = free broadcast)
//   D: convT2x2+bilinear-up+spike3; 256 threads x 1 (och,subpixel,px) unit
// LDS tiles are [thalf][ch][px] -> 16 B lane stride, conflict-free b128.
// Dataflow per global pixel identical to R1 (bit-identical output).
// ---------------------------------------------------------------------------
__global__ __launch_bounds__(256, 4)
void snn_fused(const float* __restrict__ spk,
               const float* __restrict__ wr,
               float* __restrict__ out)
{
    const int tid  = threadIdx.x;
    const int b    = blockIdx.x >> 7;
    const int tile = blockIdx.x & 127;
    const int gy0  = (tile >> 3) << 2;   // 16 y-tiles of 4 rows
    const int gx0  = (tile & 7) << 3;    // 8 x-tiles of 8 cols

    __shared__ float4 sP1[2][2][140];    // [thalf][ch][10*14 px]
    __shared__ float4 sP2[2][8][60];     // [thalf][ch][ 6*10 px]
    __shared__ float4 sP3[2][8][32];     // [thalf][ch][ 4* 8 px]
    __shared__ float  sW[1040];

    for (int i = tid; i < 1040; i += 256) sW[i] = wr[i];

    // ---- stage A: psp1 region 10x14, threads 0..139, both input channels ----
    const int ary = tid / 14, arx = tid % 14;
    const int aiy = gy0 - 3 + ary, aix = gx0 - 3 + arx;
    const bool avalid = (tid < 140) && (aiy >= 0) && (aiy < 64) && (aix >= 0) && (aix < 64);
    const int aoff0 = avalid ? (((b * 2 + 0) * 64 + aiy) * 64 + aix) * 200 : 0;
    const int aoff1 = avalid ? (((b * 2 + 1) * 64 + aiy) * 64 + aix) * 200 : 0;
    float aP0 = 0.f, aP1 = 0.f;

    // ---- stage B: 6x10 region; wave w -> och {2w, 2w+1}; lanes 0..59 ----
    const int lane = tid & 63;
    const int och0 = __builtin_amdgcn_readfirstlane(tid >> 6) * 2;
    const int by   = lane / 10, bx = lane % 10;
    float rB[2] = {0.f, 0.f}, qB[2] = {0.f, 0.f};

    // ---- stage C: 4x8 core; thread -> (och = tid>>5, px = tid&31) ----
    const int ochC = tid >> 5;
    const int cpx  = tid & 31;
    const int cy   = cpx >> 3, cx = cpx & 7;
    float rCs = 0.f, qCs = 0.f;

    // ---- stage D: thread -> (od, subpixel di/dj, px) ----
    const int od  = tid >> 7;
    const int di  = (tid >> 6) & 1;
    const int dj  = (tid >> 5) & 1;
    const int dy  = cpx >> 3, dxx = cpx & 7;
    const int diy = gy0 + dy, dix = gx0 + dxx;
    float r3 = 0.f;
    // bilinear 2x upsample weights (jax.image.resize "linear": half-pixel
    // centers, edge weights renormalized)
    const float ay  = di ? ((diy == 63) ? 1.f : 0.75f) : ((diy == 0) ? 0.f : 0.25f);
    const float byw = di ? ((diy == 63) ? 0.f : 0.25f) : ((diy == 0) ? 1.f : 0.75f);
    const float ax  = dj ? ((dix == 63) ? 1.f : 0.75f) : ((dix == 0) ? 0.f : 0.25f);
    const float bxw = dj ? ((dix == 63) ? 0.f : 0.25f) : ((dix == 0) ? 1.f : 0.75f);
    float* const op = out + ((((b * 2 + od) * 128 + (2 * diy + di)) * 128)
                             + (2 * dix + dj)) * 200;
    const int idxA = (dy + 2 + di) * 14 + (dxx + 2 + dj);   // P[di][dj]
    const int idxC = idxA + 14;                             // P[di+1][dj]

    __syncthreads();   // sW ready

#pragma unroll 1
    for (int ck = 0; ck < 25; ++ck) {
        const int t0 = ck * 8;

        // ================= stage A: psp1 =================
        if (tid < 140) {
            float4 x00, x01, x10, x11;
            if (avalid) {
                x00 = *(const float4*)(spk + aoff0 + t0);
                x01 = *(const float4*)(spk + aoff0 + t0 + 4);
                x10 = *(const float4*)(spk + aoff1 + t0);
                x11 = *(const float4*)(spk + aoff1 + t0 + 4);
            } else {
                x00 = make_float4(0.f, 0.f, 0.f, 0.f);
                x01 = x00; x10 = x00; x11 = x00;
            }
            float4 v;
            v.x = __fadd_rn(__fmul_rn(DEC1, aP0), x00.x);
            v.y = __fadd_rn(__fmul_rn(DEC1, v.x), x00.y);
            v.z = __fadd_rn(__fmul_rn(DEC1, v.y), x00.z);
            v.w = __fadd_rn(__fmul_rn(DEC1, v.z), x00.w);
            sP1[0][0][tid] = v;
            v.x = __fadd_rn(__fmul_rn(DEC1, v.w), x01.x);
            v.y = __fadd_rn(__fmul_rn(DEC1, v.x), x01.y);
            v.z = __fadd_rn(__fmul_rn(DEC1, v.y), x01.z);
            v.w = __fadd_rn(__fmul_rn(DEC1, v.z), x01.w);
            sP1[1][0][tid] = v; aP0 = v.w;
            v.x = __fadd_rn(__fmul_rn(DEC1, aP1), x10.x);
            v.y = __fadd_rn(__fmul_rn(DEC1, v.x), x10.y);
            v.z = __fadd_rn(__fmul_rn(DEC1, v.y), x10.z);
            v.w = __fadd_rn(__fmul_rn(DEC1, v.z), x10.w);
            sP1[0][1][tid] = v;
            v.x = __fadd_rn(__fmul_rn(DEC1, v.w), x11.x);
            v.y = __fadd_rn(__fmul_rn(DEC1, v.x), x11.y);
            v.z = __fadd_rn(__fmul_rn(DEC1, v.y), x11.z);
            v.w = __fadd_rn(__fmul_rn(DEC1, v.z), x11.w);
            sP1[1][1][tid] = v; aP1 = v.w;
        }
        __syncthreads();

        // ================= stage B: conv1 5x5 + spike1 + psp2 =================
        if (lane < 60) {
            float4 a00 = make_float4(0.f,0.f,0.f,0.f), a01 = a00, a10 = a00, a11 = a00;
#pragma unroll 1
            for (int c = 0; c < 2; ++c) {
#pragma unroll 1
                for (int ky = 0; ky < 5; ++ky) {
                    const float4* r0 = &sP1[0][c][(by + ky) * 14 + bx];
                    const float4* r1 = &sP1[1][c][(by + ky) * 14 + bx];
                    const float*  wrow = wr + (c * 25 + ky * 5) * 8 + och0;
#pragma unroll
                    for (int kx = 0; kx < 5; ++kx) {
                        float4 d0 = r0[kx], d1 = r1[kx];
                        float w0 = wrow[kx * 8], w1 = wrow[kx * 8 + 1];
                        FMA4(a00, w0, d0); FMA4(a01, w0, d1);
                        FMA4(a10, w1, d0); FMA4(a11, w1, d1);
                    }
                }
            }
            float4 q0 = spike_psp4(a00, 30.f, DEC1, DEC2, rB[0], qB[0]);
            float4 q1 = spike_psp4(a01, 30.f, DEC1, DEC2, rB[0], qB[0]);
            sP2[0][och0][lane] = q0; sP2[1][och0][lane] = q1;
            q0 = spike_psp4(a10, 30.f, DEC1, DEC2, rB[1], qB[1]);
            q1 = spike_psp4(a11, 30.f, DEC1, DEC2, rB[1], qB[1]);
            sP2[0][och0 + 1][lane] = q0; sP2[1][och0 + 1][lane] = q1;
        }
        __syncthreads();

        // ================= stage C: conv2 3x3 + spike2 + psp3 =================
        {
            float4 a0 = make_float4(0.f,0.f,0.f,0.f), a1 = a0;
#pragma unroll 1
            for (int c = 0; c < 8; ++c) {
#pragma unroll 1
                for (int ky = 0; ky < 3; ++ky) {
                    const float4* r0 = &sP2[0][c][(cy + ky) * 10 + cx];
                    const float4* r1 = &sP2[1][c][(cy + ky) * 10 + cx];
                    const float*  wrow = sW + 400 + (c * 9 + ky * 3) * 8 + ochC;
#pragma unroll
                    for (int kx = 0; kx < 3; ++kx) {
                        float wv = wrow[kx * 8];
                        float4 d0 = r0[kx], d1 = r1[kx];
                        FMA4(a0, wv, d0); FMA4(a1, wv, d1);
                    }
                }
            }
            float4 q0 = spike_psp4(a0, 50.f, DEC2, DEC3, rCs, qCs);
            float4 q1 = spike_psp4(a1, 50.f, DEC2, DEC3, rCs, qCs);
            sP3[0][ochC][cpx] = q0; sP3[1][ochC][cpx] = q1;
        }
        __syncthreads();

        // ========== stage D: convT 2x2 s2 + psp1 bilinear-up + spike3 ==========
        {
            float4 tv0 = make_float4(0.f,0.f,0.f,0.f), tv1 = tv0;
            const float* wD = sW + 976 + ((od * 2 + di) * 2 + dj) * 8;
#pragma unroll
            for (int c = 0; c < 8; ++c) {
                float wv = wD[c];
                float4 d0 = sP3[0][c][cpx], d1 = sP3[1][c][cpx];
                FMA4(tv0, wv, d0); FMA4(tv1, wv, d1);
            }
#pragma unroll
            for (int h = 0; h < 2; ++h) {
                float4 A  = sP1[h][od][idxA];
                float4 Bv = sP1[h][od][idxA + 1];
                float4 Cv = sP1[h][od][idxC];
                float4 Dv = sP1[h][od][idxC + 1];
                float4 tv = h ? tv1 : tv0;
                float4 up, u; float ra, rb;
                ra = __fadd_rn(__fmul_rn(ay, A.x),  __fmul_rn(byw, Cv.x));
                rb = __fadd_rn(__fmul_rn(ay, Bv.x), __fmul_rn(byw, Dv.x));
                up.x = __fadd_rn(__fmul_rn(ax, ra), __fmul_rn(bxw, rb));
                ra = __fadd_rn(__fmul_rn(ay, A.y),  __fmul_rn(byw, Cv.y));
                rb = __fadd_rn(__fmul_rn(ay, Bv.y), __fmul_rn(byw, Dv.y));
                up.y = __fadd_rn(__fmul_rn(ax, ra), __fmul_rn(bxw, rb));
                ra = __fadd_rn(__fmul_rn(ay, A.z),  __fmul_rn(byw, Cv.z));
                rb = __fadd_rn(__fmul_rn(ay, Bv.z), __fmul_rn(byw, Dv.z));
                up.z = __fadd_rn(__fmul_rn(ax, ra), __fmul_rn(bxw, rb));
                ra = __fadd_rn(__fmul_rn(ay, A.w),  __fmul_rn(byw, Cv.w));
                rb = __fadd_rn(__fmul_rn(ay, Bv.w), __fmul_rn(byw, Dv.w));
                up.w = __fadd_rn(__fmul_rn(ax, ra), __fmul_rn(bxw, rb));
                u.x = __fadd_rn(tv.x, up.x);
                u.y = __fadd_rn(tv.y, up.y);
                u.z = __fadd_rn(tv.z, up.z);
                u.w = __fadd_rn(tv.w, up.w);
                float4 ov = spike4(u, 100.f, DEC3, r3);
                *(float4*)(op + t0 + h * 4) = ov;
            }
        }
        __syncthreads();  // protect sP1/sP2/sP3 before next chunk overwrites
    }
}

extern "C" void kernel_launch(void* const* d_in, const int* in_sizes, int n_in,
                              void* d_out, int out_size, void* d_ws, size_t ws_size,
                              hipStream_t stream)
{
    const float* spk = (const float*)d_in[0];
    const float* w1  = (const float*)d_in[1];
    const float* w2  = (const float*)d_in[2];
    const float* wup = (const float*)d_in[3];
    float* outp = (float*)d_out;
    float* wr   = (float*)d_ws;   // 1040 floats of re-laid-out weights

    prep_weights<<<dim3(3), dim3(256), 0, stream>>>(w1, w2, wup, wr);
    snn_fused<<<dim3(1024), dim3(256), 0, stream>>>(spk, wr, outp);
}

// Round 5
// 711.911 us; speedup vs baseline: 1.1309x; 1.1309x over previous
//
#include <hip/hip_runtime.h>

// Correctly-rounded float decay constants
#define DEC1 0.36787944117144233f   // exp(-1)    : psp1 decay, layer1 refractory
#define DEC2 0.60653065971263342f   // exp(-1/2)  : psp2 decay, layer2 refractory
#define DEC3 0.77880078307140487f   // exp(-1/4)  : psp3 decay, layer3 refractory

// ---------------------------------------------------------------------------
// Weight re-layout into d_ws so the main kernel's weight reads are wave-uniform
// (scalar K$ loads):  w1r[c][ky][kx][o] (400 f)  w2r[c][ky][kx][o] (576 f)
// wupr[o][di][dj][c] pre-flipped for conv_transpose (64 f).  Total 1040 floats.
// ---------------------------------------------------------------------------
__global__ void prep_weights(const float* __restrict__ w1,
                             const float* __restrict__ w2,
                             const float* __restrict__ wup,
                             float* __restrict__ wr)
{
    int i = blockIdx.x * 256 + threadIdx.x;
    if (i < 400) {
        int o = i & 7, tap = i >> 3;
        int c = tap / 25, rem = tap % 25, ky = rem / 5, kx = rem % 5;
        wr[i] = w1[((o * 2 + c) * 5 + ky) * 5 + kx];
    }
    if (i < 576) {
        int o = i & 7, tap = i >> 3;
        int c = tap / 9, rem = tap % 9, ky = rem / 3, kx = rem % 3;
        wr[400 + i] = w2[((o * 8 + c) * 3 + ky) * 3 + kx];
    }
    if (i < 64) {
        // dst index i = ((o*2+di)*2+dj)*8 + c ; conv_transpose (VALID,s=2,k=2,
        // no kernel flip) gives out[2i+di] += x[i]*w[1-di]  -> store flipped.
        int c = i & 7, r = i >> 3;
        int dj = r & 1, di = (r >> 1) & 1, o = r >> 2;
        wr[976 + i] = wup[((o * 8 + c) * 2 + (1 - di)) * 2 + (1 - dj)];
    }
}

// spike + following psp, 4 consecutive timesteps (u = float4 over t)
static __device__ __forceinline__ float4 spike_psp4(float4 u, float th, float dref,
                                                    float dq, float& r, float& q)
{
    float4 qv; float v, s;
    v = __fadd_rn(u.x, r); s = (v >= th) ? 1.f : 0.f;
    r = __fsub_rn(__fmul_rn(dref, r), __fmul_rn(th, s));
    q = __fadd_rn(__fmul_rn(dq, q), s); qv.x = q;
    v = __fadd_rn(u.y, r); s = (v >= th) ? 1.f : 0.f;
    r = __fsub_rn(__fmul_rn(dref, r), __fmul_rn(th, s));
    q = __fadd_rn(__fmul_rn(dq, q), s); qv.y = q;
    v = __fadd_rn(u.z, r); s = (v >= th) ? 1.f : 0.f;
    r = __fsub_rn(__fmul_rn(dref, r), __fmul_rn(th, s));
    q = __fadd_rn(__fmul_rn(dq, q), s); qv.z = q;
    v = __fadd_rn(u.w, r); s = (v >= th) ? 1.f : 0.f;
    r = __fsub_rn(__fmul_rn(dref, r), __fmul_rn(th, s));
    q = __fadd_rn(__fmul_rn(dq, q), s); qv.w = q;
    return qv;
}

// final spike (emits hard spikes), 4 timesteps
static __device__ __forceinline__ float4 spike4(float4 u, float th, float dref, float& r)
{
    float4 ov; float v, s;
    v = __fadd_rn(u.x, r); s = (v >= th) ? 1.f : 0.f;
    r = __fsub_rn(__fmul_rn(dref, r), __fmul_rn(th, s)); ov.x = s;
    v = __fadd_rn(u.y, r); s = (v >= th) ? 1.f : 0.f;
    r = __fsub_rn(__fmul_rn(dref, r), __fmul_rn(th, s)); ov.y = s;
    v = __fadd_rn(u.z, r); s = (v >= th) ? 1.f : 0.f;
    r = __fsub_rn(__fmul_rn(dref, r), __fmul_rn(th, s)); ov.z = s;
    v = __fadd_rn(u.w, r); s = (v >= th) ? 1.f : 0.f;
    r = __fsub_rn(__fmul_rn(dref, r), __fmul_rn(th, s)); ov.w = s;
    return ov;
}

// ---------------------------------------------------------------------------
// Fused SNN megakernel, R4 = R1 (proven 560 us) with occupancy raised from
// 2 -> 4 blocks/CU via __launch_bounds__(256,4). 27.6 KB LDS permits 5
// blocks/CU; 68 VGPR fits the 128-VGPR/4-wave budget. Controlled A/B on the
// occupancy variable alone: R1's barrier drains had only 1 other co-resident
// block to hide them; now 3.
// LDS layout [ch][px] (SoA), 16 B lane stride (R1's conflict level 6.1e7).
// ---------------------------------------------------------------------------
__global__ __launch_bounds__(256, 4)
void snn_fused(const float* __restrict__ spk,
               const float* __restrict__ wr,
               float* __restrict__ out)
{
    const int tid  = threadIdx.x;
    const int b    = blockIdx.x >> 6;
    const int tile = blockIdx.x & 63;
    const int gy0  = (tile >> 3) << 3;
    const int gx0  = (tile & 7) << 3;

    __shared__ float4 sP1[2 * 196];  // [2 ch][14*14 px]  (float4 = 4 timesteps)
    __shared__ float4 sP2[8 * 100];  // [8 ch][10*10 px]
    __shared__ float4 sP3[8 * 64];   // [8 ch][ 8* 8 px]

    // persistent per-thread recurrent state
    float aP0 = 0.f, aP1 = 0.f;      // stage A psp1 state (2 input ch)
    float rB[4], qB[4];              // stage B refractory + psp2 (4 out ch)
    float rC[4], qC[4];              // stage C refractory + psp3 (4 out ch)
    float r3[4];                     // stage D refractory (4 subpixels, 1 ch)
#pragma unroll
    for (int i = 0; i < 4; ++i) { rB[i]=0.f; qB[i]=0.f; rC[i]=0.f; qC[i]=0.f; r3[i]=0.f; }

    // ---- stage A addressing: psp1 region 14x14, threads 0..195 ----
    const int ary = tid / 14, arx = tid % 14;
    const int aiy = gy0 - 3 + ary, aix = gx0 - 3 + arx;
    const bool avalid = (tid < 196) && (aiy >= 0) && (aiy < 64) && (aix >= 0) && (aix < 64);
    const int aoff0 = avalid ? (((b * 2 + 0) * 64 + aiy) * 64 + aix) * 200 : 0;
    const int aoff1 = avalid ? (((b * 2 + 1) * 64 + aiy) * 64 + aix) * 200 : 0;

    // ---- stage B: conv1(5x5)+spike1+psp2 on 10x10; waves{0,1}=ch0-3, {2,3}=ch4-7
    const int ochB = __builtin_amdgcn_readfirstlane(tid >> 7);
    const int bpx  = tid & 127;
    const int by   = bpx / 10, bx = bpx % 10;

    // ---- stage C: conv2(3x3)+spike2+psp3 on 8x8; wave0=ch0-3, wave1=ch4-7
    const int ochC = __builtin_amdgcn_readfirstlane(tid >> 6) & 1;
    const int cpx  = tid & 63;
    const int cy   = cpx >> 3, cx = cpx & 7;

    // ---- stage D: convT + bilinear-up + spike3; wave0=out ch0, wave1=out ch1
    const int od   = __builtin_amdgcn_readfirstlane(tid >> 6);
    const int dy   = cpx >> 3, dxx = cpx & 7;
    const int diy  = gy0 + dy, dix = gx0 + dxx;

    // bilinear 2x upsample weights (jax.image.resize "linear": half-pixel
    // centers, edge weights renormalized -> out edge = in edge exactly)
    const float wy0_0 = (diy == 0)  ? 0.f : 0.25f;
    const float wy1_0 = (diy == 0)  ? 1.f : 0.75f;
    const float wy0_1 = (diy == 63) ? 1.f : 0.75f;
    const float wy1_1 = (diy == 63) ? 0.f : 0.25f;
    const float wx0_0 = (dix == 0)  ? 0.f : 0.25f;
    const float wx1_0 = (dix == 0)  ? 1.f : 0.75f;
    const float wx0_1 = (dix == 63) ? 1.f : 0.75f;
    const float wx1_1 = (dix == 63) ? 0.f : 0.25f;

#pragma unroll 1
    for (int ck = 0; ck < 50; ++ck) {
        const int t0 = ck * 4;

        // ================= stage A: psp1 (leaky integrate input spikes) ====
        if (tid < 196) {
            float4 x0, x1;
            if (avalid) {
                x0 = *(const float4*)(spk + aoff0 + t0);
                x1 = *(const float4*)(spk + aoff1 + t0);
            } else {
                x0 = make_float4(0.f, 0.f, 0.f, 0.f);
                x1 = x0;
            }
            float4 v0, v1;
            v0.x = __fadd_rn(__fmul_rn(DEC1, aP0),  x0.x);
            v0.y = __fadd_rn(__fmul_rn(DEC1, v0.x), x0.y);
            v0.z = __fadd_rn(__fmul_rn(DEC1, v0.y), x0.z);
            v0.w = __fadd_rn(__fmul_rn(DEC1, v0.z), x0.w);
            aP0 = v0.w;
            v1.x = __fadd_rn(__fmul_rn(DEC1, aP1),  x1.x);
            v1.y = __fadd_rn(__fmul_rn(DEC1, v1.x), x1.y);
            v1.z = __fadd_rn(__fmul_rn(DEC1, v1.y), x1.z);
            v1.w = __fadd_rn(__fmul_rn(DEC1, v1.z), x1.w);
            aP1 = v1.w;
            sP1[0 * 196 + tid] = v0;
            sP1[1 * 196 + tid] = v1;
        }
        __syncthreads();

        // ================= stage B: conv1 5x5 + spike1 + psp2 ==============
        if (bpx < 100) {
            float4 acc[4];
#pragma unroll
            for (int j = 0; j < 4; ++j) acc[j] = make_float4(0.f, 0.f, 0.f, 0.f);
            const float* wB = wr + ochB * 4;
#pragma unroll 1
            for (int c = 0; c < 2; ++c) {
#pragma unroll 1
                for (int ky = 0; ky < 5; ++ky) {
                    const float4* rowp = &sP1[c * 196 + (by + ky) * 14 + bx];
                    const float*  wrow = wB + (c * 25 + ky * 5) * 8;
#pragma unroll
                    for (int kx = 0; kx < 5; ++kx) {
                        float4 d = rowp[kx];
#pragma unroll
                        for (int j = 0; j < 4; ++j) {
                            float w = wrow[kx * 8 + j];
                            acc[j].x += w * d.x; acc[j].y += w * d.y;
                            acc[j].z += w * d.z; acc[j].w += w * d.w;
                        }
                    }
                }
            }
#pragma unroll
            for (int j = 0; j < 4; ++j) {
                float4 qv = spike_psp4(acc[j], 30.f, DEC1, DEC2, rB[j], qB[j]);
                sP2[(ochB * 4 + j) * 100 + bpx] = qv;
            }
        }
        __syncthreads();

        // ================= stage C: conv2 3x3 + spike2 + psp3 ==============
        if (tid < 128) {
            float4 acc[4];
#pragma unroll
            for (int j = 0; j < 4; ++j) acc[j] = make_float4(0.f, 0.f, 0.f, 0.f);
            const float* wC = wr + 400 + ochC * 4;
#pragma unroll 1
            for (int c = 0; c < 8; ++c) {
#pragma unroll 1
                for (int ky = 0; ky < 3; ++ky) {
                    const float4* rowp = &sP2[c * 100 + (cy + ky) * 10 + cx];
                    const float*  wrow = wC + (c * 9 + ky * 3) * 8;
#pragma unroll
                    for (int kx = 0; kx < 3; ++kx) {
                        float4 d = rowp[kx];
#pragma unroll
                        for (int j = 0; j < 4; ++j) {
                            float w = wrow[kx * 8 + j];
                            acc[j].x += w * d.x; acc[j].y += w * d.y;
                            acc[j].z += w * d.z; acc[j].w += w * d.w;
                        }
                    }
                }
            }
#pragma unroll
            for (int j = 0; j < 4; ++j) {
                float4 qv = spike_psp4(acc[j], 50.f, DEC2, DEC3, rC[j], qC[j]);
                sP3[(ochC * 4 + j) * 64 + cpx] = qv;
            }
        }
        __syncthreads();

        // ============ stage D: convT 2x2 s2 + psp1 bilinear-up + spike3 ====
        if (tid < 128) {
            float4 p3[8];
#pragma unroll
            for (int c = 0; c < 8; ++c) p3[c] = sP3[c * 64 + cpx];
            float4 P[3][3];   // psp1 3x3 neighborhood, channel = od
#pragma unroll
            for (int sy = 0; sy < 3; ++sy)
#pragma unroll
            for (int sx = 0; sx < 3; ++sx)
                P[sy][sx] = sP1[od * 196 + (dy + 2 + sy) * 14 + (dxx + 2 + sx)];

#pragma unroll
            for (int di = 0; di < 2; ++di) {
                const float ay  = di ? wy0_1 : wy0_0;
                const float byw = di ? wy1_1 : wy1_0;
#pragma unroll
                for (int dj = 0; dj < 2; ++dj) {
                    const float ax  = dj ? wx0_1 : wx0_0;
                    const float bxw = dj ? wx1_1 : wx1_0;
                    // conv_transpose contribution (pre-flipped weights)
                    float4 tv = make_float4(0.f, 0.f, 0.f, 0.f);
                    const float* wD = wr + 976 + ((od * 2 + di) * 2 + dj) * 8;
#pragma unroll
                    for (int c = 0; c < 8; ++c) {
                        float w = wD[c];
                        tv.x += w * p3[c].x; tv.y += w * p3[c].y;
                        tv.z += w * p3[c].z; tv.w += w * p3[c].w;
                    }
                    // bilinear upsample: y-interp first (resize does H then W)
                    float4 A = P[di][dj],     Bv = P[di][dj + 1];
                    float4 Cv = P[di + 1][dj], Dv = P[di + 1][dj + 1];
                    float4 up, u;
                    float ra, rb;
                    ra = __fadd_rn(__fmul_rn(ay, A.x),  __fmul_rn(byw, Cv.x));
                    rb = __fadd_rn(__fmul_rn(ay, Bv.x), __fmul_rn(byw, Dv.x));
                    up.x = __fadd_rn(__fmul_rn(ax, ra), __fmul_rn(bxw, rb));
                    ra = __fadd_rn(__fmul_rn(ay, A.y),  __fmul_rn(byw, Cv.y));
                    rb = __fadd_rn(__fmul_rn(ay, Bv.y), __fmul_rn(byw, Dv.y));
                    up.y = __fadd_rn(__fmul_rn(ax, ra), __fmul_rn(bxw, rb));
                    ra = __fadd_rn(__fmul_rn(ay, A.z),  __fmul_rn(byw, Cv.z));
                    rb = __fadd_rn(__fmul_rn(ay, Bv.z), __fmul_rn(byw, Dv.z));
                    up.z = __fadd_rn(__fmul_rn(ax, ra), __fmul_rn(bxw, rb));
                    ra = __fadd_rn(__fmul_rn(ay, A.w),  __fmul_rn(byw, Cv.w));
                    rb = __fadd_rn(__fmul_rn(ay, Bv.w), __fmul_rn(byw, Dv.w));
                    up.w = __fadd_rn(__fmul_rn(ax, ra), __fmul_rn(bxw, rb));

                    u.x = __fadd_rn(tv.x, up.x);
                    u.y = __fadd_rn(tv.y, up.y);
                    u.z = __fadd_rn(tv.z, up.z);
                    u.w = __fadd_rn(tv.w, up.w);

                    const int sub = di * 2 + dj;
                    float4 ov = spike4(u, 100.f, DEC3, r3[sub]);
                    float* op = out + ((((b * 2 + od) * 128 + (2 * diy + di)) * 128)
                                       + (2 * dix + dj)) * 200 + t0;
                    *(float4*)op = ov;
                }
            }
        }
        __syncthreads();  // protect sP1/sP3 before next chunk overwrites
    }
}

extern "C" void kernel_launch(void* const* d_in, const int* in_sizes, int n_in,
                              void* d_out, int out_size, void* d_ws, size_t ws_size,
                              hipStream_t stream)
{
    const float* spk = (const float*)d_in[0];
    const float* w1  = (const float*)d_in[1];
    const float* w2  = (const float*)d_in[2];
    const float* wup = (const float*)d_in[3];
    float* outp = (float*)d_out;
    float* wr   = (float*)d_ws;   // 1040 floats of re-laid-out weights

    prep_weights<<<dim3(3), dim3(256), 0, stream>>>(w1, w2, wup, wr);
    snn_fused<<<dim3(512), dim3(256), 0, stream>>>(spk, wr, outp);
}

// Round 6
// 654.113 us; speedup vs baseline: 1.2309x; 1.0884x over previous
//
#include <hip/hip_runtime.h>

// Correctly-rounded float decay constants
#define DEC1 0.36787944117144233f   // exp(-1)    : psp1 decay, layer1 refractory
#define DEC2 0.60653065971263342f   // exp(-1/2)  : psp2 decay, layer2 refractory
#define DEC3 0.77880078307140487f   // exp(-1/4)  : psp3 decay, layer3 refractory

// ---------------------------------------------------------------------------
// Weight re-layout into d_ws:  w1r[c][ky][kx][o] (400 f)  w2r[c][ky][kx][o]
// (576 f)  wupr[o][di][dj][c] pre-flipped for conv_transpose (64 f).
// ---------------------------------------------------------------------------
__global__ void prep_weights(const float* __restrict__ w1,
                             const float* __restrict__ w2,
                             const float* __restrict__ wup,
                             float* __restrict__ wr)
{
    int i = blockIdx.x * 256 + threadIdx.x;
    if (i < 400) {
        int o = i & 7, tap = i >> 3;
        int c = tap / 25, rem = tap % 25, ky = rem / 5, kx = rem % 5;
        wr[i] = w1[((o * 2 + c) * 5 + ky) * 5 + kx];
    }
    if (i < 576) {
        int o = i & 7, tap = i >> 3;
        int c = tap / 9, rem = tap % 9, ky = rem / 3, kx = rem % 3;
        wr[400 + i] = w2[((o * 8 + c) * 3 + ky) * 3 + kx];
    }
    if (i < 64) {
        int c = i & 7, r = i >> 3;
        int dj = r & 1, di = (r >> 1) & 1, o = r >> 2;
        wr[976 + i] = wup[((o * 8 + c) * 2 + (1 - di)) * 2 + (1 - dj)];
    }
}

// spike + following psp, 4 consecutive timesteps (u = float4 over t)
static __device__ __forceinline__ float4 spike_psp4(float4 u, float th, float dref,
                                                    float dq, float& r, float& q)
{
    float4 qv; float v, s;
    v = __fadd_rn(u.x, r); s = (v >= th) ? 1.f : 0.f;
    r = __fsub_rn(__fmul_rn(dref, r), __fmul_rn(th, s));
    q = __fadd_rn(__fmul_rn(dq, q), s); qv.x = q;
    v = __fadd_rn(u.y, r); s = (v >= th) ? 1.f : 0.f;
    r = __fsub_rn(__fmul_rn(dref, r), __fmul_rn(th, s));
    q = __fadd_rn(__fmul_rn(dq, q), s); qv.y = q;
    v = __fadd_rn(u.z, r); s = (v >= th) ? 1.f : 0.f;
    r = __fsub_rn(__fmul_rn(dref, r), __fmul_rn(th, s));
    q = __fadd_rn(__fmul_rn(dq, q), s); qv.z = q;
    v = __fadd_rn(u.w, r); s = (v >= th) ? 1.f : 0.f;
    r = __fsub_rn(__fmul_rn(dref, r), __fmul_rn(th, s));
    q = __fadd_rn(__fmul_rn(dq, q), s); qv.w = q;
    return qv;
}

// final spike (emits hard spikes), 4 timesteps
static __device__ __forceinline__ float4 spike4(float4 u, float th, float dref, float& r)
{
    float4 ov; float v, s;
    v = __fadd_rn(u.x, r); s = (v >= th) ? 1.f : 0.f;
    r = __fsub_rn(__fmul_rn(dref, r), __fmul_rn(th, s)); ov.x = s;
    v = __fadd_rn(u.y, r); s = (v >= th) ? 1.f : 0.f;
    r = __fsub_rn(__fmul_rn(dref, r), __fmul_rn(th, s)); ov.y = s;
    v = __fadd_rn(u.z, r); s = (v >= th) ? 1.f : 0.f;
    r = __fsub_rn(__fmul_rn(dref, r), __fmul_rn(th, s)); ov.z = s;
    v = __fadd_rn(u.w, r); s = (v >= th) ? 1.f : 0.f;
    r = __fsub_rn(__fmul_rn(dref, r), __fmul_rn(th, s)); ov.w = s;
    return ov;
}

// macro params must not be named w/x/y/z (member-capture, R2 failure)
#define FMA4(ACC_, W_, D_) { ACC_.x += (W_)*(D_).x; ACC_.y += (W_)*(D_).y; \
                             ACC_.z += (W_)*(D_).z; ACC_.w += (W_)*(D_).w; }

// psp1 leaky-integrate 4 steps: state in `st`, input X_, write V_ out
#define PSP4(V_, X_, st) { \
    V_.x = __fadd_rn(__fmul_rn(DEC1, st),   X_.x); \
    V_.y = __fadd_rn(__fmul_rn(DEC1, V_.x), X_.y); \
    V_.z = __fadd_rn(__fmul_rn(DEC1, V_.y), X_.z); \
    V_.w = __fadd_rn(__fmul_rn(DEC1, V_.z), X_.w); st = V_.w; }

// ---------------------------------------------------------------------------
// R5 = R1 structure (proven best: low LDS amplification, 6.1e7 conflicts) +
//  (1) T-chunk 8: 25 chunks, per-barrier work doubled
//  (2) register prefetch of next chunk's input (HBM latency overlaps B-D)
//  (3) sP1 parity double-buffer -> drop end-of-loop barrier: 75 barriers total
// 2 blocks/CU (grid 512 = hard cap; 67 KB LDS also caps at 2).
// launch_bounds(256,2): 256-VGPR budget, no spill.
// Per-unit arithmetic order identical to R1 -> bit-identical output.
// ---------------------------------------------------------------------------
__global__ __launch_bounds__(256, 2)
void snn_fused(const float* __restrict__ spk,
               const float* __restrict__ wr,
               float* __restrict__ out)
{
    const int tid  = threadIdx.x;
    const int b    = blockIdx.x >> 6;
    const int tile = blockIdx.x & 63;
    const int gy0  = (tile >> 3) << 3;
    const int gx0  = (tile & 7) << 3;

    __shared__ float4 sP1[2][2][2][196]; // [parity][ch][thalf][14*14 px] 25.1 KB
    __shared__ float4 sP2[8][2][100];    // [ch][thalf][10*10 px]         25.6 KB
    __shared__ float4 sP3[8][2][64];     // [ch][thalf][ 8* 8 px]         16.4 KB

    // persistent per-thread recurrent state
    float aP0 = 0.f, aP1 = 0.f;
    float rB[4], qB[4], rC[4], qC[4], r3[4];
#pragma unroll
    for (int i = 0; i < 4; ++i) { rB[i]=0.f; qB[i]=0.f; rC[i]=0.f; qC[i]=0.f; r3[i]=0.f; }

    // ---- stage A addressing: psp1 region 14x14, threads 0..195 ----
    const int ary = tid / 14, arx = tid % 14;
    const int aiy = gy0 - 3 + ary, aix = gx0 - 3 + arx;
    const bool avalid = (tid < 196) && (aiy >= 0) && (aiy < 64) && (aix >= 0) && (aix < 64);
    const int aoff0 = avalid ? (((b * 2 + 0) * 64 + aiy) * 64 + aix) * 200 : 0;
    const int aoff1 = avalid ? (((b * 2 + 1) * 64 + aiy) * 64 + aix) * 200 : 0;

    // ---- stage B: 10x10 region; waves{0,1}=och0-3, waves{2,3}=och4-7 ----
    const int ochB = __builtin_amdgcn_readfirstlane(tid >> 7);
    const int bpx  = tid & 127;
    const int by   = bpx / 10, bx = bpx % 10;

    // ---- stage C: 8x8 core; wave0=och0-3, wave1=och4-7 ----
    const int ochC = __builtin_amdgcn_readfirstlane(tid >> 6) & 1;
    const int cpx  = tid & 63;
    const int cy   = cpx >> 3, cx = cpx & 7;

    // ---- stage D: wave0=out ch0, wave1=out ch1 ----
    const int od   = __builtin_amdgcn_readfirstlane(tid >> 6);
    const int dy   = cpx >> 3, dxx = cpx & 7;
    const int diy  = gy0 + dy, dix = gx0 + dxx;

    // bilinear 2x upsample weights (jax.image.resize "linear")
    const float wy0_0 = (diy == 0)  ? 0.f : 0.25f;
    const float wy1_0 = (diy == 0)  ? 1.f : 0.75f;
    const float wy0_1 = (diy == 63) ? 1.f : 0.75f;
    const float wy1_1 = (diy == 63) ? 0.f : 0.25f;
    const float wx0_0 = (dix == 0)  ? 0.f : 0.25f;
    const float wx1_0 = (dix == 0)  ? 1.f : 0.75f;
    const float wx0_1 = (dix == 63) ? 1.f : 0.75f;
    const float wx1_1 = (dix == 63) ? 0.f : 0.25f;

    // ---- prefetch registers: chunk 0's input ----
    float4 x00 = make_float4(0.f,0.f,0.f,0.f), x01 = x00, x10 = x00, x11 = x00;
    if (avalid) {
        x00 = *(const float4*)(spk + aoff0);
        x01 = *(const float4*)(spk + aoff0 + 4);
        x10 = *(const float4*)(spk + aoff1);
        x11 = *(const float4*)(spk + aoff1 + 4);
    }

#pragma unroll 1
    for (int ck = 0; ck < 25; ++ck) {
        const int t0 = ck * 8;
        const int p  = ck & 1;

        // ================= stage A: psp1 + prefetch next chunk =============
        if (tid < 196) {
            float4 v;
            PSP4(v, x00, aP0); sP1[p][0][0][tid] = v;
            PSP4(v, x01, aP0); sP1[p][0][1][tid] = v;
            PSP4(v, x10, aP1); sP1[p][1][0][tid] = v;
            PSP4(v, x11, aP1); sP1[p][1][1][tid] = v;
            if (ck < 24 && avalid) {   // prefetch chunk ck+1 (overlaps B-D)
                x00 = *(const float4*)(spk + aoff0 + t0 + 8);
                x01 = *(const float4*)(spk + aoff0 + t0 + 12);
                x10 = *(const float4*)(spk + aoff1 + t0 + 8);
                x11 = *(const float4*)(spk + aoff1 + t0 + 12);
            }
        }
        __syncthreads();   // b1: sP1[p] ready (also orders prev-C reads vs B writes)

        // ================= stage B: conv1 5x5 + spike1 + psp2 ==============
        if (bpx < 100) {
            float4 a0[4], a1[4];
#pragma unroll
            for (int j = 0; j < 4; ++j) { a0[j] = make_float4(0.f,0.f,0.f,0.f); a1[j] = a0[j]; }
            const float* wB = wr + ochB * 4;
#pragma unroll 1
            for (int c = 0; c < 2; ++c) {
#pragma unroll 1
                for (int ky = 0; ky < 5; ++ky) {
                    const float4* r0 = &sP1[p][c][0][(by + ky) * 14 + bx];
                    const float4* r1 = &sP1[p][c][1][(by + ky) * 14 + bx];
                    const float*  wrow = wB + (c * 25 + ky * 5) * 8;
#pragma unroll
                    for (int kx = 0; kx < 5; ++kx) {
                        float4 d0 = r0[kx], d1 = r1[kx];
#pragma unroll
                        for (int j = 0; j < 4; ++j) {
                            float wv = wrow[kx * 8 + j];
                            FMA4(a0[j], wv, d0); FMA4(a1[j], wv, d1);
                        }
                    }
                }
            }
#pragma unroll
            for (int j = 0; j < 4; ++j) {
                float4 q0 = spike_psp4(a0[j], 30.f, DEC1, DEC2, rB[j], qB[j]);
                sP2[ochB * 4 + j][0][bpx] = q0;
                float4 q1 = spike_psp4(a1[j], 30.f, DEC1, DEC2, rB[j], qB[j]);
                sP2[ochB * 4 + j][1][bpx] = q1;
            }
        }
        __syncthreads();   // b2

        // ================= stage C: conv2 3x3 + spike2 + psp3 ==============
        if (tid < 128) {
            float4 a0[4], a1[4];
#pragma unroll
            for (int j = 0; j < 4; ++j) { a0[j] = make_float4(0.f,0.f,0.f,0.f); a1[j] = a0[j]; }
            const float* wC = wr + 400 + ochC * 4;
#pragma unroll 1
            for (int c = 0; c < 8; ++c) {
#pragma unroll 1
                for (int ky = 0; ky < 3; ++ky) {
                    const float4* r0 = &sP2[c][0][(cy + ky) * 10 + cx];
                    const float4* r1 = &sP2[c][1][(cy + ky) * 10 + cx];
                    const float*  wrow = wC + (c * 9 + ky * 3) * 8;
#pragma unroll
                    for (int kx = 0; kx < 3; ++kx) {
                        float4 d0 = r0[kx], d1 = r1[kx];
#pragma unroll
                        for (int j = 0; j < 4; ++j) {
                            float wv = wrow[kx * 8 + j];
                            FMA4(a0[j], wv, d0); FMA4(a1[j], wv, d1);
                        }
                    }
                }
            }
#pragma unroll
            for (int j = 0; j < 4; ++j) {
                float4 q0 = spike_psp4(a0[j], 50.f, DEC2, DEC3, rC[j], qC[j]);
                sP3[ochC * 4 + j][0][cpx] = q0;
                float4 q1 = spike_psp4(a1[j], 50.f, DEC2, DEC3, rC[j], qC[j]);
                sP3[ochC * 4 + j][1][cpx] = q1;
            }
        }
        __syncthreads();   // b3

        // ============ stage D: convT 2x2 s2 + psp1 bilinear-up + spike3 ====
        if (tid < 128) {
#pragma unroll 1
            for (int h = 0; h < 2; ++h) {
                float4 p3[8];
#pragma unroll
                for (int c = 0; c < 8; ++c) p3[c] = sP3[c][h][cpx];
                float4 P[3][3];
#pragma unroll
                for (int sy = 0; sy < 3; ++sy)
#pragma unroll
                for (int sx = 0; sx < 3; ++sx)
                    P[sy][sx] = sP1[p][od][h][(dy + 2 + sy) * 14 + (dxx + 2 + sx)];

#pragma unroll
                for (int di = 0; di < 2; ++di) {
                    const float ay  = di ? wy0_1 : wy0_0;
                    const float byw = di ? wy1_1 : wy1_0;
#pragma unroll
                    for (int dj = 0; dj < 2; ++dj) {
                        const float ax  = dj ? wx0_1 : wx0_0;
                        const float bxw = dj ? wx1_1 : wx1_0;
                        float4 tv = make_float4(0.f, 0.f, 0.f, 0.f);
                        const float* wD = wr + 976 + ((od * 2 + di) * 2 + dj) * 8;
#pragma unroll
                        for (int c = 0; c < 8; ++c) {
                            float wv = wD[c];
                            FMA4(tv, wv, p3[c]);
                        }
                        float4 A = P[di][dj],      Bv = P[di][dj + 1];
                        float4 Cv = P[di + 1][dj], Dv = P[di + 1][dj + 1];
                        float4 up, u; float ra, rb;
                        ra = __fadd_rn(__fmul_rn(ay, A.x),  __fmul_rn(byw, Cv.x));
                        rb = __fadd_rn(__fmul_rn(ay, Bv.x), __fmul_rn(byw, Dv.x));
                        up.x = __fadd_rn(__fmul_rn(ax, ra), __fmul_rn(bxw, rb));
                        ra = __fadd_rn(__fmul_rn(ay, A.y),  __fmul_rn(byw, Cv.y));
                        rb = __fadd_rn(__fmul_rn(ay, Bv.y), __fmul_rn(byw, Dv.y));
                        up.y = __fadd_rn(__fmul_rn(ax, ra), __fmul_rn(bxw, rb));
                        ra = __fadd_rn(__fmul_rn(ay, A.z),  __fmul_rn(byw, Cv.z));
                        rb = __fadd_rn(__fmul_rn(ay, Bv.z), __fmul_rn(byw, Dv.z));
                        up.z = __fadd_rn(__fmul_rn(ax, ra), __fmul_rn(bxw, rb));
                        ra = __fadd_rn(__fmul_rn(ay, A.w),  __fmul_rn(byw, Cv.w));
                        rb = __fadd_rn(__fmul_rn(ay, Bv.w), __fmul_rn(byw, Dv.w));
                        up.w = __fadd_rn(__fmul_rn(ax, ra), __fmul_rn(bxw, rb));
                        u.x = __fadd_rn(tv.x, up.x);
                        u.y = __fadd_rn(tv.y, up.y);
                        u.z = __fadd_rn(tv.z, up.z);
                        u.w = __fadd_rn(tv.w, up.w);
                        const int sub = di * 2 + dj;
                        float4 ov = spike4(u, 100.f, DEC3, r3[sub]);
                        float* op = out + ((((b * 2 + od) * 128 + (2 * diy + di)) * 128)
                                           + (2 * dix + dj)) * 200 + t0 + h * 4;
                        *(float4*)op = ov;
                    }
                }
            }
        }
        // no end barrier: next A writes sP1[p^1]; sP3/sP2 protected by b1'/b2'
    }
}

extern "C" void kernel_launch(void* const* d_in, const int* in_sizes, int n_in,
                              void* d_out, int out_size, void* d_ws, size_t ws_size,
                              hipStream_t stream)
{
    const float* spk = (const float*)d_in[0];
    const float* w1  = (const float*)d_in[1];
    const float* w2  = (const float*)d_in[2];
    const float* wup = (const float*)d_in[3];
    float* outp = (float*)d_out;
    float* wr   = (float*)d_ws;   // 1040 floats of re-laid-out weights

    prep_weights<<<dim3(3), dim3(256), 0, stream>>>(w1, w2, wup, wr);
    snn_fused<<<dim3(512), dim3(256), 0, stream>>>(spk, wr, outp);
}

// Round 7
// 603.777 us; speedup vs baseline: 1.3335x; 1.0834x over previous
//
#include <hip/hip_runtime.h>

// Correctly-rounded float decay constants
#define DEC1 0.36787944117144233f   // exp(-1)    : psp1 decay, layer1 refractory
#define DEC2 0.60653065971263342f   // exp(-1/2)  : psp2 decay, layer2 refractory
#define DEC3 0.77880078307140487f   // exp(-1/4)  : psp3 decay, layer3 refractory

// ---------------------------------------------------------------------------
// Weight re-layout into d_ws:  w1r[c][ky][kx][o] (400 f)  w2r[c][ky][kx][o]
// (576 f)  wupr[o][di][dj][c] pre-flipped for conv_transpose (64 f).
// ---------------------------------------------------------------------------
__global__ void prep_weights(const float* __restrict__ w1,
                             const float* __restrict__ w2,
                             const float* __restrict__ wup,
                             float* __restrict__ wr)
{
    int i = blockIdx.x * 256 + threadIdx.x;
    if (i < 400) {
        int o = i & 7, tap = i >> 3;
        int c = tap / 25, rem = tap % 25, ky = rem / 5, kx = rem % 5;
        wr[i] = w1[((o * 2 + c) * 5 + ky) * 5 + kx];
    }
    if (i < 576) {
        int o = i & 7, tap = i >> 3;
        int c = tap / 9, rem = tap % 9, ky = rem / 3, kx = rem % 3;
        wr[400 + i] = w2[((o * 8 + c) * 3 + ky) * 3 + kx];
    }
    if (i < 64) {
        int c = i & 7, r = i >> 3;
        int dj = r & 1, di = (r >> 1) & 1, o = r >> 2;
        wr[976 + i] = wup[((o * 8 + c) * 2 + (1 - di)) * 2 + (1 - dj)];
    }
}

// spike + following psp, 4 consecutive timesteps (u = float4 over t)
static __device__ __forceinline__ float4 spike_psp4(float4 u, float th, float dref,
                                                    float dq, float& r, float& q)
{
    float4 qv; float v, s;
    v = __fadd_rn(u.x, r); s = (v >= th) ? 1.f : 0.f;
    r = __fsub_rn(__fmul_rn(dref, r), __fmul_rn(th, s));
    q = __fadd_rn(__fmul_rn(dq, q), s); qv.x = q;
    v = __fadd_rn(u.y, r); s = (v >= th) ? 1.f : 0.f;
    r = __fsub_rn(__fmul_rn(dref, r), __fmul_rn(th, s));
    q = __fadd_rn(__fmul_rn(dq, q), s); qv.y = q;
    v = __fadd_rn(u.z, r); s = (v >= th) ? 1.f : 0.f;
    r = __fsub_rn(__fmul_rn(dref, r), __fmul_rn(th, s));
    q = __fadd_rn(__fmul_rn(dq, q), s); qv.z = q;
    v = __fadd_rn(u.w, r); s = (v >= th) ? 1.f : 0.f;
    r = __fsub_rn(__fmul_rn(dref, r), __fmul_rn(th, s));
    q = __fadd_rn(__fmul_rn(dq, q), s); qv.w = q;
    return qv;
}

// final spike (emits hard spikes), 4 timesteps
static __device__ __forceinline__ float4 spike4(float4 u, float th, float dref, float& r)
{
    float4 ov; float v, s;
    v = __fadd_rn(u.x, r); s = (v >= th) ? 1.f : 0.f;
    r = __fsub_rn(__fmul_rn(dref, r), __fmul_rn(th, s)); ov.x = s;
    v = __fadd_rn(u.y, r); s = (v >= th) ? 1.f : 0.f;
    r = __fsub_rn(__fmul_rn(dref, r), __fmul_rn(th, s)); ov.y = s;
    v = __fadd_rn(u.z, r); s = (v >= th) ? 1.f : 0.f;
    r = __fsub_rn(__fmul_rn(dref, r), __fmul_rn(th, s)); ov.z = s;
    v = __fadd_rn(u.w, r); s = (v >= th) ? 1.f : 0.f;
    r = __fsub_rn(__fmul_rn(dref, r), __fmul_rn(th, s)); ov.w = s;
    return ov;
}

// macro params must not be named w/x/y/z (member-capture, R2 failure)
#define FMA4(ACC_, W_, D_) { ACC_.x += (W_)*(D_).x; ACC_.y += (W_)*(D_).y; \
                             ACC_.z += (W_)*(D_).z; ACC_.w += (W_)*(D_).w; }

// psp1 leaky-integrate 4 steps: state in `st`, input X_, write V_ out
#define PSP4(V_, X_, st) { \
    V_.x = __fadd_rn(__fmul_rn(DEC1, st),   X_.x); \
    V_.y = __fadd_rn(__fmul_rn(DEC1, V_.x), X_.y); \
    V_.z = __fadd_rn(__fmul_rn(DEC1, V_.y), X_.z); \
    V_.w = __fadd_rn(__fmul_rn(DEC1, V_.z), X_.w); st = V_.w; }

// ---------------------------------------------------------------------------
// R6 = R5 skeleton (chunk 8, sP1 parity dbuf, 3 barriers/chunk, prefetch) +
//  (a) sP1 rows padded to 16 float4s + stage-B px remap with bx 8-aligned
//      (kills the 10-wide-row bank-quad duplication = most of the 6.1e7
//      conflict cycles; C/D/A patterns were already bank-clean)
//  (b) stage C spread over ALL 4 waves: wave w -> och pair {2w,2w+1},
//      64 px/lane, both t-halves in-thread (recurrence stays per-thread).
//      2x sP2 read amplification (conflict-free) buys 2x VALU spread --
//      SIMDs 2,3 no longer idle in the biggest stage.
//  (c) stage D spread over ALL 4 waves: thread = (od, di, px), dj in-thread.
// Per-unit arithmetic order identical -> bit-identical output.
// LDS 70656 B -> still 2 blocks/CU.
// ---------------------------------------------------------------------------
__global__ __launch_bounds__(256, 2)
void snn_fused(const float* __restrict__ spk,
               const float* __restrict__ wr,
               float* __restrict__ out)
{
    const int tid  = threadIdx.x;
    const int b    = blockIdx.x >> 6;
    const int tile = blockIdx.x & 63;
    const int gy0  = (tile >> 3) << 3;
    const int gx0  = (tile & 7) << 3;

    __shared__ float4 sP1[2][2][2][224]; // [parity][ch][thalf][14 rows x 16]
    __shared__ float4 sP2[8][2][100];    // [ch][thalf][10x10 px]
    __shared__ float4 sP3[8][2][64];     // [ch][thalf][ 8x8 px]

    // persistent per-thread recurrent state
    float aP0 = 0.f, aP1 = 0.f;
    float rB[4], qB[4];
    float rC[2] = {0.f, 0.f}, qC[2] = {0.f, 0.f};
    float r3[2] = {0.f, 0.f};
#pragma unroll
    for (int i = 0; i < 4; ++i) { rB[i] = 0.f; qB[i] = 0.f; }

    // ---- stage A: psp1 region 14x14, threads 0..195 ----
    const int ary = tid / 14, arx = tid % 14;
    const int aidx = ary * 16 + arx;           // padded row stride 16
    const int aiy = gy0 - 3 + ary, aix = gx0 - 3 + arx;
    const bool avalid = (tid < 196) && (aiy >= 0) && (aiy < 64) && (aix >= 0) && (aix < 64);
    const int aoff0 = avalid ? (((b * 2 + 0) * 64 + aiy) * 64 + aix) * 200 : 0;
    const int aoff1 = avalid ? (((b * 2 + 1) * 64 + aiy) * 64 + aix) * 200 : 0;

    // ---- stage B: 10x10 region; waves{0,1}=och0-3, {2,3}=och4-7 ----
    // px->lane remap: lanes 0..79 of the pair cover bx 0..7 (bank-aligned),
    // lanes 80..99 cover the bx 8..9 tail.
    const int ochB = __builtin_amdgcn_readfirstlane(tid >> 7);
    const int bpx  = tid & 127;
    int by_, bx_;
    if (bpx < 80) { by_ = bpx >> 3; bx_ = bpx & 7; }
    else          { int t2 = bpx - 80; by_ = t2 >> 1; bx_ = 8 + (t2 & 1); }
    const int by = by_, bx = bx_;
    const int bwr = by * 10 + bx;              // sP2 write index (bijective)

    // ---- stage C: all 256 threads; wave w -> och {2w, 2w+1}; px = lane ----
    const int wvC  = __builtin_amdgcn_readfirstlane(tid >> 6);
    const int ochC = wvC * 2;
    const int cpx  = tid & 63;
    const int cy   = cpx >> 3, cx = cpx & 7;

    // ---- stage D: all 256 threads; thread = (od = t>>7, di = (t>>6)&1, px) ----
    const int od  = tid >> 7;
    const int ddi = (tid >> 6) & 1;
    const int dpx = tid & 63;
    const int dy  = dpx >> 3, dxx = dpx & 7;
    const int diy = gy0 + dy, dix = gx0 + dxx;

    // bilinear 2x upsample weights (jax.image.resize "linear")
    const float ay  = ddi ? ((diy == 63) ? 1.f : 0.75f) : ((diy == 0) ? 0.f : 0.25f);
    const float byw = ddi ? ((diy == 63) ? 0.f : 0.25f) : ((diy == 0) ? 1.f : 0.75f);
    const float ax0 = (dix == 0)  ? 0.f : 0.25f;   // dj = 0
    const float bx0 = (dix == 0)  ? 1.f : 0.75f;
    const float ax1 = (dix == 63) ? 1.f : 0.75f;   // dj = 1
    const float bx1 = (dix == 63) ? 0.f : 0.25f;
    const int   didx = (dy + 2 + ddi) * 16 + (dxx + 2);  // P row 0 base (padded)

    // ---- prefetch registers: chunk 0's input ----
    float4 x00 = make_float4(0.f,0.f,0.f,0.f), x01 = x00, x10 = x00, x11 = x00;
    if (avalid) {
        x00 = *(const float4*)(spk + aoff0);
        x01 = *(const float4*)(spk + aoff0 + 4);
        x10 = *(const float4*)(spk + aoff1);
        x11 = *(const float4*)(spk + aoff1 + 4);
    }

#pragma unroll 1
    for (int ck = 0; ck < 25; ++ck) {
        const int t0 = ck * 8;
        const int p  = ck & 1;

        // ================= stage A: psp1 + prefetch next chunk =============
        if (tid < 196) {
            float4 v;
            PSP4(v, x00, aP0); sP1[p][0][0][aidx] = v;
            PSP4(v, x01, aP0); sP1[p][0][1][aidx] = v;
            PSP4(v, x10, aP1); sP1[p][1][0][aidx] = v;
            PSP4(v, x11, aP1); sP1[p][1][1][aidx] = v;
            if (ck < 24 && avalid) {
                x00 = *(const float4*)(spk + aoff0 + t0 + 8);
                x01 = *(const float4*)(spk + aoff0 + t0 + 12);
                x10 = *(const float4*)(spk + aoff1 + t0 + 8);
                x11 = *(const float4*)(spk + aoff1 + t0 + 12);
            }
        }
        __syncthreads();   // b1: sP1[p] ready

        // ================= stage B: conv1 5x5 + spike1 + psp2 ==============
        if (bpx < 100) {
            float4 a0[4], a1[4];
#pragma unroll
            for (int j = 0; j < 4; ++j) { a0[j] = make_float4(0.f,0.f,0.f,0.f); a1[j] = a0[j]; }
            const float* wB = wr + ochB * 4;
#pragma unroll 1
            for (int c = 0; c < 2; ++c) {
#pragma unroll 1
                for (int ky = 0; ky < 5; ++ky) {
                    const float4* r0 = &sP1[p][c][0][(by + ky) * 16 + bx];
                    const float4* r1 = &sP1[p][c][1][(by + ky) * 16 + bx];
                    const float*  wrow = wB + (c * 25 + ky * 5) * 8;
#pragma unroll
                    for (int kx = 0; kx < 5; ++kx) {
                        float4 d0 = r0[kx], d1 = r1[kx];
#pragma unroll
                        for (int j = 0; j < 4; ++j) {
                            float wv = wrow[kx * 8 + j];
                            FMA4(a0[j], wv, d0); FMA4(a1[j], wv, d1);
                        }
                    }
                }
            }
#pragma unroll
            for (int j = 0; j < 4; ++j) {
                float4 q0 = spike_psp4(a0[j], 30.f, DEC1, DEC2, rB[j], qB[j]);
                sP2[ochB * 4 + j][0][bwr] = q0;
                float4 q1 = spike_psp4(a1[j], 30.f, DEC1, DEC2, rB[j], qB[j]);
                sP2[ochB * 4 + j][1][bwr] = q1;
            }
        }
        __syncthreads();   // b2

        // ================= stage C: conv2 3x3 + spike2 + psp3 ==============
        {
            float4 a00 = make_float4(0.f,0.f,0.f,0.f), a01 = a00, a10 = a00, a11 = a00;
            const float* wC = wr + 400 + ochC;
#pragma unroll 1
            for (int c = 0; c < 8; ++c) {
#pragma unroll 1
                for (int ky = 0; ky < 3; ++ky) {
                    const float4* r0 = &sP2[c][0][(cy + ky) * 10 + cx];
                    const float4* r1 = &sP2[c][1][(cy + ky) * 10 + cx];
                    const float*  wrow = wC + (c * 9 + ky * 3) * 8;
#pragma unroll
                    for (int kx = 0; kx < 3; ++kx) {
                        float4 d0 = r0[kx], d1 = r1[kx];
                        float w0 = wrow[kx * 8], w1 = wrow[kx * 8 + 1];
                        FMA4(a00, w0, d0); FMA4(a01, w0, d1);
                        FMA4(a10, w1, d0); FMA4(a11, w1, d1);
                    }
                }
            }
            float4 qv;
            qv = spike_psp4(a00, 50.f, DEC2, DEC3, rC[0], qC[0]); sP3[ochC][0][cpx] = qv;
            qv = spike_psp4(a01, 50.f, DEC2, DEC3, rC[0], qC[0]); sP3[ochC][1][cpx] = qv;
            qv = spike_psp4(a10, 50.f, DEC2, DEC3, rC[1], qC[1]); sP3[ochC + 1][0][cpx] = qv;
            qv = spike_psp4(a11, 50.f, DEC2, DEC3, rC[1], qC[1]); sP3[ochC + 1][1][cpx] = qv;
        }
        __syncthreads();   // b3

        // ============ stage D: convT 2x2 s2 + psp1 bilinear-up + spike3 ====
        {
#pragma unroll 1
            for (int h = 0; h < 2; ++h) {
                float4 p3[8];
#pragma unroll
                for (int c = 0; c < 8; ++c) p3[c] = sP3[c][h][dpx];
                // psp1 neighborhood: 2 rows x 3 cols (row pair ddi, ddi+1)
                float4 P0a = sP1[p][od][h][didx];
                float4 P0b = sP1[p][od][h][didx + 1];
                float4 P0c = sP1[p][od][h][didx + 2];
                float4 P1a = sP1[p][od][h][didx + 16];
                float4 P1b = sP1[p][od][h][didx + 17];
                float4 P1c = sP1[p][od][h][didx + 18];
#pragma unroll
                for (int dj = 0; dj < 2; ++dj) {
                    const float ax  = dj ? ax1 : ax0;
                    const float bxw = dj ? bx1 : bx0;
                    float4 tv = make_float4(0.f, 0.f, 0.f, 0.f);
                    const float* wD = wr + 976 + ((od * 2 + ddi) * 2 + dj) * 8;
#pragma unroll
                    for (int c = 0; c < 8; ++c) {
                        float wv = wD[c];
                        FMA4(tv, wv, p3[c]);
                    }
                    float4 A  = dj ? P0b : P0a;
                    float4 Bv = dj ? P0c : P0b;
                    float4 Cv = dj ? P1b : P1a;
                    float4 Dv = dj ? P1c : P1b;
                    float4 up, u; float ra, rb;
                    ra = __fadd_rn(__fmul_rn(ay, A.x),  __fmul_rn(byw, Cv.x));
                    rb = __fadd_rn(__fmul_rn(ay, Bv.x), __fmul_rn(byw, Dv.x));
                    up.x = __fadd_rn(__fmul_rn(ax, ra), __fmul_rn(bxw, rb));
                    ra = __fadd_rn(__fmul_rn(ay, A.y),  __fmul_rn(byw, Cv.y));
                    rb = __fadd_rn(__fmul_rn(ay, Bv.y), __fmul_rn(byw, Dv.y));
                    up.y = __fadd_rn(__fmul_rn(ax, ra), __fmul_rn(bxw, rb));
                    ra = __fadd_rn(__fmul_rn(ay, A.z),  __fmul_rn(byw, Cv.z));
                    rb = __fadd_rn(__fmul_rn(ay, Bv.z), __fmul_rn(byw, Dv.z));
                    up.z = __fadd_rn(__fmul_rn(ax, ra), __fmul_rn(bxw, rb));
                    ra = __fadd_rn(__fmul_rn(ay, A.w),  __fmul_rn(byw, Cv.w));
                    rb = __fadd_rn(__fmul_rn(ay, Bv.w), __fmul_rn(byw, Dv.w));
                    up.w = __fadd_rn(__fmul_rn(ax, ra), __fmul_rn(bxw, rb));
                    u.x = __fadd_rn(tv.x, up.x);
                    u.y = __fadd_rn(tv.y, up.y);
                    u.z = __fadd_rn(tv.z, up.z);
                    u.w = __fadd_rn(tv.w, up.w);
                    float4 ov = spike4(u, 100.f, DEC3, r3[dj]);
                    float* op = out + ((((b * 2 + od) * 128 + (2 * diy + ddi)) * 128)
                                       + (2 * dix + dj)) * 200 + t0 + h * 4;
                    *(float4*)op = ov;
                }
            }
        }
        // no end barrier: next A writes sP1[p^1]; sP2/sP3 protected by b1'/b2'
    }
}

extern "C" void kernel_launch(void* const* d_in, const int* in_sizes, int n_in,
                              void* d_out, int out_size, void* d_ws, size_t ws_size,
                              hipStream_t stream)
{
    const float* spk = (const float*)d_in[0];
    const float* w1  = (const float*)d_in[1];
    const float* w2  = (const float*)d_in[2];
    const float* wup = (const float*)d_in[3];
    float* outp = (float*)d_out;
    float* wr   = (float*)d_ws;   // 1040 floats of re-laid-out weights

    prep_weights<<<dim3(3), dim3(256), 0, stream>>>(w1, w2, wup, wr);
    snn_fused<<<dim3(512), dim3(256), 0, stream>>>(spk, wr, outp);
}

// Round 8
// 570.621 us; speedup vs baseline: 1.4110x; 1.0581x over previous
//
#include <hip/hip_runtime.h>

// Correctly-rounded float decay constants
#define DEC1 0.36787944117144233f   // exp(-1)    : psp1 decay, layer1 refractory
#define DEC2 0.60653065971263342f   // exp(-1/2)  : psp2 decay, layer2 refractory
#define DEC3 0.77880078307140487f   // exp(-1/4)  : psp3 decay, layer3 refractory

// ---------------------------------------------------------------------------
// Weight re-layout into d_ws:  w1r[c][ky][kx][o] (400 f)  w2r[c][ky][kx][o]
// (576 f)  wupr[o][di][dj][c] pre-flipped for conv_transpose (64 f).
// ---------------------------------------------------------------------------
__global__ void prep_weights(const float* __restrict__ w1,
                             const float* __restrict__ w2,
                             const float* __restrict__ wup,
                             float* __restrict__ wr)
{
    int i = blockIdx.x * 256 + threadIdx.x;
    if (i < 400) {
        int o = i & 7, tap = i >> 3;
        int c = tap / 25, rem = tap % 25, ky = rem / 5, kx = rem % 5;
        wr[i] = w1[((o * 2 + c) * 5 + ky) * 5 + kx];
    }
    if (i < 576) {
        int o = i & 7, tap = i >> 3;
        int c = tap / 9, rem = tap % 9, ky = rem / 3, kx = rem % 3;
        wr[400 + i] = w2[((o * 8 + c) * 3 + ky) * 3 + kx];
    }
    if (i < 64) {
        int c = i & 7, r = i >> 3;
        int dj = r & 1, di = (r >> 1) & 1, o = r >> 2;
        wr[976 + i] = wup[((o * 8 + c) * 2 + (1 - di)) * 2 + (1 - dj)];
    }
}

// spike + following psp, 4 consecutive timesteps (u = float4 over t)
static __device__ __forceinline__ float4 spike_psp4(float4 u, float th, float dref,
                                                    float dq, float& r, float& q)
{
    float4 qv; float v, s;
    v = __fadd_rn(u.x, r); s = (v >= th) ? 1.f : 0.f;
    r = __fsub_rn(__fmul_rn(dref, r), __fmul_rn(th, s));
    q = __fadd_rn(__fmul_rn(dq, q), s); qv.x = q;
    v = __fadd_rn(u.y, r); s = (v >= th) ? 1.f : 0.f;
    r = __fsub_rn(__fmul_rn(dref, r), __fmul_rn(th, s));
    q = __fadd_rn(__fmul_rn(dq, q), s); qv.y = q;
    v = __fadd_rn(u.z, r); s = (v >= th) ? 1.f : 0.f;
    r = __fsub_rn(__fmul_rn(dref, r), __fmul_rn(th, s));
    q = __fadd_rn(__fmul_rn(dq, q), s); qv.z = q;
    v = __fadd_rn(u.w, r); s = (v >= th) ? 1.f : 0.f;
    r = __fsub_rn(__fmul_rn(dref, r), __fmul_rn(th, s));
    q = __fadd_rn(__fmul_rn(dq, q), s); qv.w = q;
    return qv;
}

// final spike (emits hard spikes), 4 timesteps
static __device__ __forceinline__ float4 spike4(float4 u, float th, float dref, float& r)
{
    float4 ov; float v, s;
    v = __fadd_rn(u.x, r); s = (v >= th) ? 1.f : 0.f;
    r = __fsub_rn(__fmul_rn(dref, r), __fmul_rn(th, s)); ov.x = s;
    v = __fadd_rn(u.y, r); s = (v >= th) ? 1.f : 0.f;
    r = __fsub_rn(__fmul_rn(dref, r), __fmul_rn(th, s)); ov.y = s;
    v = __fadd_rn(u.z, r); s = (v >= th) ? 1.f : 0.f;
    r = __fsub_rn(__fmul_rn(dref, r), __fmul_rn(th, s)); ov.z = s;
    v = __fadd_rn(u.w, r); s = (v >= th) ? 1.f : 0.f;
    r = __fsub_rn(__fmul_rn(dref, r), __fmul_rn(th, s)); ov.w = s;
    return ov;
}

// macro params must not be named w/x/y/z (member-capture, R2 failure)
#define FMA4(ACC_, W_, D_) { ACC_.x += (W_)*(D_).x; ACC_.y += (W_)*(D_).y; \
                             ACC_.z += (W_)*(D_).z; ACC_.w += (W_)*(D_).w; }

// psp1 leaky-integrate 4 steps: state in `st`, input X_, write V_ out
#define PSP4(V_, X_, st) { \
    V_.x = __fadd_rn(__fmul_rn(DEC1, st),   X_.x); \
    V_.y = __fadd_rn(__fmul_rn(DEC1, V_.x), X_.y); \
    V_.z = __fadd_rn(__fmul_rn(DEC1, V_.y), X_.z); \
    V_.w = __fadd_rn(__fmul_rn(DEC1, V_.z), X_.w); st = V_.w; }

// ---------------------------------------------------------------------------
// R7 = R6 skeleton (chunk 8, sP1 parity dbuf, prefetch, padded sP1) with
// conv/recurrence split to cut LDS reads ~35% (LDS pipe was ~78% busy):
//   B-conv: thread = (h, px<100) computes ALL 8 och for ONE t-half ->
//           50 sP1 reads/thread (was 100); acc written to sP2 slots.
//   B-rec:  in-place spike+psp on sP2 (each thread owns its slots; same
//           state mapping & arithmetic order as R6 -> bit-identical).
//   C-conv: thread = (h, och-quad, px) -> 72 sP2 reads/thread (was 144).
//   C-rec:  in-place on sP3.
// 5 barriers/chunk (was 3) -- R5 data says barrier marginal cost << the
// ~290k LDS cycles/CU saved. LDS total unchanged (70656 B, 2 blocks/CU).
// ---------------------------------------------------------------------------
__global__ __launch_bounds__(256, 2)
void snn_fused(const float* __restrict__ spk,
               const float* __restrict__ wr,
               float* __restrict__ out)
{
    const int tid  = threadIdx.x;
    const int b    = blockIdx.x >> 6;
    const int tile = blockIdx.x & 63;
    const int gy0  = (tile >> 3) << 3;
    const int gx0  = (tile & 7) << 3;

    __shared__ float4 sP1[2][2][2][224]; // [parity][ch][thalf][14 rows x 16]
    __shared__ float4 sP2[8][2][100];    // [ch][thalf][10x10 px] (acc then psp2)
    __shared__ float4 sP3[8][2][64];     // [ch][thalf][ 8x8 px]  (acc then psp3)

    // persistent per-thread recurrent state
    float aP0 = 0.f, aP1 = 0.f;
    float rB[4], qB[4];
    float rC[2] = {0.f, 0.f}, qC[2] = {0.f, 0.f};
    float r3[2] = {0.f, 0.f};
#pragma unroll
    for (int i = 0; i < 4; ++i) { rB[i] = 0.f; qB[i] = 0.f; }

    // ---- stage A: psp1 region 14x14, threads 0..195 ----
    const int ary = tid / 14, arx = tid % 14;
    const int aidx = ary * 16 + arx;           // padded row stride 16
    const int aiy = gy0 - 3 + ary, aix = gx0 - 3 + arx;
    const bool avalid = (tid < 196) && (aiy >= 0) && (aiy < 64) && (aix >= 0) && (aix < 64);
    const int aoff0 = avalid ? (((b * 2 + 0) * 64 + aiy) * 64 + aix) * 200 : 0;
    const int aoff1 = avalid ? (((b * 2 + 1) * 64 + aiy) * 64 + aix) * 200 : 0;

    // ---- stage B: thread = (bh = tid>>7, bpx = tid&127 < 100) ----
    // px->lane remap keeps bx 8-aligned for bank-clean sP1 reads.
    const int bh   = __builtin_amdgcn_readfirstlane(tid >> 7);
    const int bpx  = tid & 127;
    int by_, bx_;
    if (bpx < 80) { by_ = bpx >> 3; bx_ = bpx & 7; }
    else          { int t2 = bpx - 80; by_ = t2 >> 1; bx_ = 8 + (t2 & 1); }
    const int by = by_, bx = bx_;
    const int bwr = by * 10 + bx;              // sP2 px index (bijective)
    // B-rec mapping (state owner, same as R6): och quad = tid>>7
    const int ochB = tid >> 7;

    // ---- C-conv: thread = (ch2 = tid>>7, cop = (tid>>6)&1 -> och quad, px) ----
    const int ch2  = __builtin_amdgcn_readfirstlane(tid >> 7);
    const int cop  = __builtin_amdgcn_readfirstlane(tid >> 6) & 1;
    const int cpx  = tid & 63;
    const int cy   = cpx >> 3, cx = cpx & 7;
    // C-rec mapping: och pair = tid>>6, px = tid&63
    const int och2 = (tid >> 6) * 2;

    // ---- stage D: thread = (od = t>>7, ddi = (t>>6)&1, px) ----
    const int od  = tid >> 7;
    const int ddi = (tid >> 6) & 1;
    const int dpx = tid & 63;
    const int dy  = dpx >> 3, dxx = dpx & 7;
    const int diy = gy0 + dy, dix = gx0 + dxx;

    // bilinear 2x upsample weights (jax.image.resize "linear")
    const float ay  = ddi ? ((diy == 63) ? 1.f : 0.75f) : ((diy == 0) ? 0.f : 0.25f);
    const float byw = ddi ? ((diy == 63) ? 0.f : 0.25f) : ((diy == 0) ? 1.f : 0.75f);
    const float ax0 = (dix == 0)  ? 0.f : 0.25f;   // dj = 0
    const float bx0 = (dix == 0)  ? 1.f : 0.75f;
    const float ax1 = (dix == 63) ? 1.f : 0.75f;   // dj = 1
    const float bx1 = (dix == 63) ? 0.f : 0.25f;
    const int   didx = (dy + 2 + ddi) * 16 + (dxx + 2);

    // ---- prefetch registers: chunk 0's input ----
    float4 x00 = make_float4(0.f,0.f,0.f,0.f), x01 = x00, x10 = x00, x11 = x00;
    if (avalid) {
        x00 = *(const float4*)(spk + aoff0);
        x01 = *(const float4*)(spk + aoff0 + 4);
        x10 = *(const float4*)(spk + aoff1);
        x11 = *(const float4*)(spk + aoff1 + 4);
    }

#pragma unroll 1
    for (int ck = 0; ck < 25; ++ck) {
        const int t0 = ck * 8;
        const int p  = ck & 1;

        // ================= stage A: psp1 + prefetch next chunk =============
        if (tid < 196) {
            float4 v;
            PSP4(v, x00, aP0); sP1[p][0][0][aidx] = v;
            PSP4(v, x01, aP0); sP1[p][0][1][aidx] = v;
            PSP4(v, x10, aP1); sP1[p][1][0][aidx] = v;
            PSP4(v, x11, aP1); sP1[p][1][1][aidx] = v;
            if (ck < 24 && avalid) {
                x00 = *(const float4*)(spk + aoff0 + t0 + 8);
                x01 = *(const float4*)(spk + aoff0 + t0 + 12);
                x10 = *(const float4*)(spk + aoff1 + t0 + 8);
                x11 = *(const float4*)(spk + aoff1 + t0 + 12);
            }
        }
        __syncthreads();   // b1: sP1[p] ready; prev-chunk C-conv done with sP2

        // ============ stage B-conv: conv1 5x5, all 8 och, one t-half =======
        if (bpx < 100) {
            float4 a[8];
#pragma unroll
            for (int o = 0; o < 8; ++o) a[o] = make_float4(0.f,0.f,0.f,0.f);
#pragma unroll 1
            for (int c = 0; c < 2; ++c) {
#pragma unroll 1
                for (int ky = 0; ky < 5; ++ky) {
                    const float4* r0 = &sP1[p][c][bh][(by + ky) * 16 + bx];
                    const float*  wrow = wr + (c * 25 + ky * 5) * 8;
#pragma unroll
                    for (int kx = 0; kx < 5; ++kx) {
                        float4 d = r0[kx];
#pragma unroll
                        for (int o = 0; o < 8; ++o) {
                            float wv = wrow[kx * 8 + o];
                            FMA4(a[o], wv, d);
                        }
                    }
                }
            }
#pragma unroll
            for (int o = 0; o < 8; ++o) sP2[o][bh][bwr] = a[o];
        }
        __syncthreads();   // b2: acc ready

        // ============ stage B-rec: spike1 + psp2 in-place on sP2 ===========
        if (bpx < 100) {
#pragma unroll
            for (int j = 0; j < 4; ++j) {
                const int o = ochB * 4 + j;
                float4 u0 = sP2[o][0][bwr];
                float4 u1 = sP2[o][1][bwr];
                float4 q0 = spike_psp4(u0, 30.f, DEC1, DEC2, rB[j], qB[j]);
                sP2[o][0][bwr] = q0;
                float4 q1 = spike_psp4(u1, 30.f, DEC1, DEC2, rB[j], qB[j]);
                sP2[o][1][bwr] = q1;
            }
        }
        __syncthreads();   // b3: psp2 ready

        // ============ stage C-conv: conv2 3x3, och quad, one t-half ========
        {
            float4 a[4];
#pragma unroll
            for (int j = 0; j < 4; ++j) a[j] = make_float4(0.f,0.f,0.f,0.f);
            const float* wC = wr + 400 + cop * 4;
#pragma unroll 1
            for (int c = 0; c < 8; ++c) {
#pragma unroll 1
                for (int ky = 0; ky < 3; ++ky) {
                    const float4* r0 = &sP2[c][ch2][(cy + ky) * 10 + cx];
                    const float*  wrow = wC + (c * 9 + ky * 3) * 8;
#pragma unroll
                    for (int kx = 0; kx < 3; ++kx) {
                        float4 d = r0[kx];
#pragma unroll
                        for (int j = 0; j < 4; ++j) {
                            float wv = wrow[kx * 8 + j];
                            FMA4(a[j], wv, d);
                        }
                    }
                }
            }
#pragma unroll
            for (int j = 0; j < 4; ++j) sP3[cop * 4 + j][ch2][cpx] = a[j];
        }
        __syncthreads();   // b4: acc ready

        // ============ stage C-rec: spike2 + psp3 in-place on sP3 ===========
        {
#pragma unroll
            for (int j = 0; j < 2; ++j) {
                const int o = och2 + j;
                float4 u0 = sP3[o][0][cpx];
                float4 u1 = sP3[o][1][cpx];
                float4 q0 = spike_psp4(u0, 50.f, DEC2, DEC3, rC[j], qC[j]);
                sP3[o][0][cpx] = q0;
                float4 q1 = spike_psp4(u1, 50.f, DEC2, DEC3, rC[j], qC[j]);
                sP3[o][1][cpx] = q1;
            }
        }
        __syncthreads();   // b5: psp3 ready

        // ============ stage D: convT 2x2 s2 + psp1 bilinear-up + spike3 ====
        {
#pragma unroll 1
            for (int h = 0; h < 2; ++h) {
                float4 p3[8];
#pragma unroll
                for (int c = 0; c < 8; ++c) p3[c] = sP3[c][h][dpx];
                float4 P0a = sP1[p][od][h][didx];
                float4 P0b = sP1[p][od][h][didx + 1];
                float4 P0c = sP1[p][od][h][didx + 2];
                float4 P1a = sP1[p][od][h][didx + 16];
                float4 P1b = sP1[p][od][h][didx + 17];
                float4 P1c = sP1[p][od][h][didx + 18];
#pragma unroll
                for (int dj = 0; dj < 2; ++dj) {
                    const float ax  = dj ? ax1 : ax0;
                    const float bxw = dj ? bx1 : bx0;
                    float4 tv = make_float4(0.f, 0.f, 0.f, 0.f);
                    const float* wD = wr + 976 + ((od * 2 + ddi) * 2 + dj) * 8;
#pragma unroll
                    for (int c = 0; c < 8; ++c) {
                        float wv = wD[c];
                        FMA4(tv, wv, p3[c]);
                    }
                    float4 A  = dj ? P0b : P0a;
                    float4 Bv = dj ? P0c : P0b;
                    float4 Cv = dj ? P1b : P1a;
                    float4 Dv = dj ? P1c : P1b;
                    float4 up, u; float ra, rb;
                    ra = __fadd_rn(__fmul_rn(ay, A.x),  __fmul_rn(byw, Cv.x));
                    rb = __fadd_rn(__fmul_rn(ay, Bv.x), __fmul_rn(byw, Dv.x));
                    up.x = __fadd_rn(__fmul_rn(ax, ra), __fmul_rn(bxw, rb));
                    ra = __fadd_rn(__fmul_rn(ay, A.y),  __fmul_rn(byw, Cv.y));
                    rb = __fadd_rn(__fmul_rn(ay, Bv.y), __fmul_rn(byw, Dv.y));
                    up.y = __fadd_rn(__fmul_rn(ax, ra), __fmul_rn(bxw, rb));
                    ra = __fadd_rn(__fmul_rn(ay, A.z),  __fmul_rn(byw, Cv.z));
                    rb = __fadd_rn(__fmul_rn(ay, Bv.z), __fmul_rn(byw, Dv.z));
                    up.z = __fadd_rn(__fmul_rn(ax, ra), __fmul_rn(bxw, rb));
                    ra = __fadd_rn(__fmul_rn(ay, A.w),  __fmul_rn(byw, Cv.w));
                    rb = __fadd_rn(__fmul_rn(ay, Bv.w), __fmul_rn(byw, Dv.w));
                    up.w = __fadd_rn(__fmul_rn(ax, ra), __fmul_rn(bxw, rb));
                    u.x = __fadd_rn(tv.x, up.x);
                    u.y = __fadd_rn(tv.y, up.y);
                    u.z = __fadd_rn(tv.z, up.z);
                    u.w = __fadd_rn(tv.w, up.w);
                    float4 ov = spike4(u, 100.f, DEC3, r3[dj]);
                    float* op = out + ((((b * 2 + od) * 128 + (2 * diy + ddi)) * 128)
                                       + (2 * dix + dj)) * 200 + t0 + h * 4;
                    *(float4*)op = ov;
                }
            }
        }
        // no end barrier: next A writes sP1[p^1]; sP2 safe until next B-conv
        // (separated by b1'); sP3 safe until next C-conv (separated by b3').
    }
}

extern "C" void kernel_launch(void* const* d_in, const int* in_sizes, int n_in,
                              void* d_out, int out_size, void* d_ws, size_t ws_size,
                              hipStream_t stream)
{
    const float* spk = (const float*)d_in[0];
    const float* w1  = (const float*)d_in[1];
    const float* w2  = (const float*)d_in[2];
    const float* wup = (const float*)d_in[3];
    float* outp = (float*)d_out;
    float* wr   = (float*)d_ws;   // 1040 floats of re-laid-out weights

    prep_weights<<<dim3(3), dim3(256), 0, stream>>>(w1, w2, wup, wr);
    snn_fused<<<dim3(512), dim3(256), 0, stream>>>(spk, wr, outp);
}